// Round 5
// baseline (1182.809 us; speedup 1.0000x reference)
//
#include <hip/hip_runtime.h>
#include <hip/hip_bf16.h>

// Swin stage: B=64 H=W=56 D=128 WS=7 NH=4 L=2 HID=512, downsample 4D->2D.
// Round 5: GEMM rebuilt — global_load_lds(16B) staging with pre-swizzled
// source + XOR-swizzled conflict-free frag reads (linear LDS, rule #21),
// and LDS-transpose epilogue with wide coalesced stores for every EPI.

typedef short bf16x8 __attribute__((ext_vector_type(8)));
typedef float f32x4 __attribute__((ext_vector_type(4)));
typedef unsigned short u16;
typedef unsigned int u32;

#define MTOK 200704   // B*H*W tokens
#define DSTOK 50176   // B*28*28

__device__ __forceinline__ u16 f2b(float f){
  u32 u = __float_as_uint(f);
  u += 0x7fffu + ((u >> 16) & 1u);
  return (u16)(u >> 16);
}
__device__ __forceinline__ float blo(u32 u){ return __uint_as_float(u << 16); }
__device__ __forceinline__ float bhi(u32 u){ return __uint_as_float(u & 0xffff0000u); }

__device__ __forceinline__ float gelu_tanh(float v){
  float u = 0.7978845608028654f * (v + 0.044715f * v * v * v);
  u = fminf(u, 10.f);
  float e = __expf(2.f * u);
  float t = (e - 1.f) / (e + 1.f);
  return 0.5f * v * (1.f + t);
}

// ---------------- weight transpose + bf16 cast: src[K][N] f32 -> dst[N][K] bf16
__global__ void transpose_cvt(const float* __restrict__ src, u16* __restrict__ dst,
                              int K, int N){
  int e = blockIdx.x * 256 + threadIdx.x;
  if (e >= K * N) return;
  int k = e / N, n = e - k * N;
  dst[n * K + k] = f2b(src[e]);
}

// ---------------- LayerNorm pass -> bf16 rows
// MODE 0: window order, no shift; MODE 1: window order, shift +3; MODE 2: linear
template<int MODE>
__global__ __launch_bounds__(256) void ln_kernel(const float* __restrict__ src,
    const float* __restrict__ gw, const float* __restrict__ bw,
    u16* __restrict__ dst)
{
  int wv = threadIdx.x >> 6, lane = threadIdx.x & 63;
  int t = blockIdx.x * 4 + wv;
  long soff;
  if (MODE == 2) {
    soff = (long)t * 128;
  } else {
    int n = t % 49; int tq = t / 49; int gg = tq & 63; int b_ = tq >> 6;
    int r = n / 7, c = n - 7 * r;
    int h = (gg >> 3) * 7 + r, w = (gg & 7) * 7 + c;
    if (MODE == 1) { h += 3; if (h >= 56) h -= 56; w += 3; if (w >= 56) w -= 56; }
    soff = ((long)((b_ * 56 + h) * 56 + w)) * 128;
  }
  float2 v = *(const float2*)(src + soff + lane * 2);
  float s = v.x + v.y, s2 = v.x * v.x + v.y * v.y;
  #pragma unroll
  for (int o = 32; o; o >>= 1) { s += __shfl_xor(s, o); s2 += __shfl_xor(s2, o); }
  float mean = s * 0.0078125f;
  float var  = s2 * 0.0078125f - mean * mean;
  float rstd = rsqrtf(var + 1e-5f);
  int c0 = lane * 2;
  ushort2 o2;
  o2.x = f2b((v.x - mean) * rstd * gw[c0]   + bw[c0]);
  o2.y = f2b((v.y - mean) * rstd * gw[c0+1] + bw[c0+1]);
  *(ushort2*)(dst + (long)t * 128 + c0) = o2;
}

// ---------------- downsample gather + LN(512) -> bf16 rows [DSTOK][512]
__global__ __launch_bounds__(256) void ds_ln_kernel(const float* __restrict__ x,
    const float* __restrict__ gw, const float* __restrict__ bw,
    u16* __restrict__ dst)
{
  int wv = threadIdx.x >> 6, lane = threadIdx.x & 63;
  int t = blockIdx.x * 4 + wv;                  // 0..50175
  int j = t % 28; int tq = t / 28; int i = tq % 28; int b_ = tq / 28;
  int e0 = lane * 8;
  int p = e0 >> 8, q = (e0 >> 7) & 1, d = e0 & 127;
  const float* src = x + ((long)((b_ * 56 + 2*i + p) * 56 + 2*j + q)) * 128 + d;
  float4 a  = *(const float4*)src;
  float4 b4 = *(const float4*)(src + 4);
  float vs[8] = {a.x, a.y, a.z, a.w, b4.x, b4.y, b4.z, b4.w};
  float s = 0.f, s2 = 0.f;
  #pragma unroll
  for (int u = 0; u < 8; u++) { s += vs[u]; s2 += vs[u] * vs[u]; }
  #pragma unroll
  for (int o = 32; o; o >>= 1) { s += __shfl_xor(s, o); s2 += __shfl_xor(s2, o); }
  float mean = s * (1.f / 512.f);
  float var  = s2 * (1.f / 512.f) - mean * mean;
  float rstd = rsqrtf(var + 1e-5f);
  u16 ov[8];
  #pragma unroll
  for (int u = 0; u < 8; u++) ov[u] = f2b((vs[u] - mean) * rstd * gw[e0+u] + bw[e0+u]);
  uint4 o4;
  o4.x = (u32)ov[0] | ((u32)ov[1] << 16);
  o4.y = (u32)ov[2] | ((u32)ov[3] << 16);
  o4.z = (u32)ov[4] | ((u32)ov[5] << 16);
  o4.w = (u32)ov[6] | ((u32)ov[7] << 16);
  *(uint4*)(dst + (long)t * 512 + e0) = o4;
}

// ---------------- MFMA window attention (unchanged from round 4)
template<int MASKED>
__global__ __launch_bounds__(256) void attn_mfma(const u16* __restrict__ qkv,
                                                 u16* __restrict__ obuf)
{
  __shared__ u16 Pls_all[4][64][72];
  const int h = threadIdx.x >> 6;
  const int lane = threadIdx.x & 63;
  const int c = lane & 15, g = lane >> 4;
  const int wi = blockIdx.x;
  const int g_ = wi & 63;
  const long t0 = (long)wi * 49;
  u16 (*Pls)[72] = Pls_all[h];

  bf16x8 qf[4], kf[4];
  #pragma unroll
  for (int mi = 0; mi < 4; mi++) {
    int r = 16*mi + c; r = r > 48 ? 48 : r;
    qf[mi] = *(const bf16x8*)(qkv + (t0 + r)*384 + h*32 + g*8);
  }
  #pragma unroll
  for (int ni = 0; ni < 4; ni++) {
    int r = 16*ni + c; r = r > 48 ? 48 : r;
    kf[ni] = *(const bf16x8*)(qkv + (t0 + r)*384 + 128 + h*32 + g*8);
  }

  f32x4 acc[4][4];
  const f32x4 zero4 = {0.f, 0.f, 0.f, 0.f};
  #pragma unroll
  for (int mi = 0; mi < 4; mi++)
    #pragma unroll
    for (int ni = 0; ni < 4; ni++)
      acc[mi][ni] = __builtin_amdgcn_mfma_f32_16x16x32_bf16(qf[mi], kf[ni], zero4, 0, 0, 0);

  bf16x8 vf[2][2];
  #pragma unroll
  for (int ni2 = 0; ni2 < 2; ni2++)
    #pragma unroll
    for (int ks = 0; ks < 2; ks++)
      #pragma unroll
      for (int jj = 0; jj < 8; jj++) {
        int k = ks*32 + 8*g + jj; k = k > 48 ? 48 : k;
        vf[ni2][ks][jj] = (short)qkv[(t0 + k)*384 + 256 + h*32 + 16*ni2 + c];
      }

  int rid_c[4];
  int g1b = 0, g2b = 0;
  if (MASKED) {
    g1b = (g_ >> 3) * 7; g2b = (g_ & 7) * 7;
    #pragma unroll
    for (int ni = 0; ni < 4; ni++) {
      int col = 16*ni + c; col = col > 48 ? 48 : col;
      int cr = col / 7, cc = col - 7*cr;
      int hh = g1b + cr, ww = g2b + cc;
      rid_c[ni] = (hh < 49 ? 0 : (hh < 53 ? 1 : 2)) * 3 + (ww < 49 ? 0 : (ww < 53 ? 1 : 2));
    }
  }

  #pragma unroll
  for (int mi = 0; mi < 4; mi++) {
    #pragma unroll
    for (int j = 0; j < 4; j++) {
      int rr = 16*mi + 4*g + j;
      int rid_r = 0;
      if (MASKED) {
        int r2 = rr > 48 ? 48 : rr;
        int rh = r2 / 7, rw = r2 - 7*rh;
        int hh = g1b + rh, ww = g2b + rw;
        rid_r = (hh < 49 ? 0 : (hh < 53 ? 1 : 2)) * 3 + (ww < 49 ? 0 : (ww < 53 ? 1 : 2));
      }
      float sv[4];
      #pragma unroll
      for (int ni = 0; ni < 4; ni++) {
        float s = acc[mi][ni][j] * 0.17677669529663687f;
        int col = 16*ni + c;
        if (col >= 49) s = -1e30f;
        else if (MASKED && rid_c[ni] != rid_r) s -= 100.f;
        sv[ni] = s;
      }
      float m4 = fmaxf(fmaxf(sv[0], sv[1]), fmaxf(sv[2], sv[3]));
      #pragma unroll
      for (int o = 1; o <= 8; o <<= 1) m4 = fmaxf(m4, __shfl_xor(m4, o));
      float p[4], sum = 0.f;
      #pragma unroll
      for (int ni = 0; ni < 4; ni++) { p[ni] = __expf(sv[ni] - m4); sum += p[ni]; }
      #pragma unroll
      for (int o = 1; o <= 8; o <<= 1) sum += __shfl_xor(sum, o);
      float rs = 1.f / sum;
      #pragma unroll
      for (int ni = 0; ni < 4; ni++)
        Pls[rr][16*ni + c] = f2b(p[ni] * rs);
    }
  }

  __syncthreads();

  f32x4 accO[4][2];
  #pragma unroll
  for (int mi = 0; mi < 4; mi++)
    #pragma unroll
    for (int ni2 = 0; ni2 < 2; ni2++) accO[mi][ni2] = zero4;
  #pragma unroll
  for (int mi = 0; mi < 4; mi++)
    #pragma unroll
    for (int ks = 0; ks < 2; ks++) {
      bf16x8 pa = *(const bf16x8*)(&Pls[16*mi + c][ks*32 + g*8]);
      #pragma unroll
      for (int ni2 = 0; ni2 < 2; ni2++)
        accO[mi][ni2] = __builtin_amdgcn_mfma_f32_16x16x32_bf16(pa, vf[ni2][ks], accO[mi][ni2], 0, 0, 0);
    }

  #pragma unroll
  for (int mi = 0; mi < 4; mi++)
    #pragma unroll
    for (int ni2 = 0; ni2 < 2; ni2++)
      #pragma unroll
      for (int j = 0; j < 4; j++) {
        int r = 16*mi + 4*g + j;
        if (r < 49)
          obuf[(t0 + r)*128 + h*32 + 16*ni2 + c] = f2b(accO[mi][ni2][j]);
      }
}

// ---------------- MFMA GEMM: C[M,Ntot] = A[M,K](bf16) * Bt[Ntot,K]^T (bf16)
// 128x128 tile, 4 waves, BK=64. Staging via global_load_lds(16B) into LINEAR
// LDS with pre-swizzled global source; frag reads XOR-swizzled (conflict-free).
// Epilogue: two 64-row halves through swizzled f32 LDS -> wide coalesced stores.
// EPI: 0 bias->bf16 | 1 bias+gelu->bf16 | 2 bias+residual f32 scatter (window->x)
//      3 bias, outf += (linear)         | 4 plain f32 store
template<int K, int EPI>
__global__ __launch_bounds__(256) void gemm_kernel(
    const u16* __restrict__ A, const u16* __restrict__ Bt,
    const float* __restrict__ bias, int Ntot,
    u16* __restrict__ outb, float* __restrict__ outf,
    const float* __restrict__ resbase, int shift)
{
  __shared__ __align__(16) u16 sh[16384];      // 32 KB: As 16K | Bs 16K; C aliases all
  u16* Asl = sh;                                // [128][64] linear, swizzled content
  u16* Bsl = sh + 8192;
  float (*Cf)[128] = (float(*)[128])sh;         // 64 x 128 f32 (epilogue alias)

  const int tid = threadIdx.x;
  const int row0 = blockIdx.x * 128, col0 = blockIdx.y * 128;
  const int wv = tid >> 6, lane = tid & 63;
  const int m_off = (wv >> 1) * 64, n_off = (wv & 1) * 64;
  const int lr = lane & 15, lk = (lane >> 4) * 8;

  f32x4 acc[4][4];
  const f32x4 zero4 = {0.f, 0.f, 0.f, 0.f};
  #pragma unroll
  for (int a1 = 0; a1 < 4; a1++)
    #pragma unroll
    for (int a2 = 0; a2 < 4; a2++) acc[a1][a2] = zero4;

  for (int k0 = 0; k0 < K; k0 += 64) {
    __syncthreads();
    // stage A and B tiles: 1024 chunks of 16B each; per-wave lds dests are
    // lane-consecutive (m104); source col pre-swizzled so frag reads can XOR.
    #pragma unroll
    for (int j = 0; j < 4; j++) {
      int ch = tid + j * 256;
      int r = ch >> 3, cc = ch & 7;
      int col = k0 + ((cc * 8) ^ ((r & 7) << 3));
      __builtin_amdgcn_global_load_lds(
          (const __attribute__((address_space(1))) u32*)(A + (long)(row0 + r) * K + col),
          (__attribute__((address_space(3))) u32*)(Asl + ch * 8), 16, 0, 0);
      __builtin_amdgcn_global_load_lds(
          (const __attribute__((address_space(1))) u32*)(Bt + (long)(col0 + r) * K + col),
          (__attribute__((address_space(3))) u32*)(Bsl + ch * 8), 16, 0, 0);
    }
    __syncthreads();   // compiler drains vmcnt before barrier
    #pragma unroll
    for (int kk = 0; kk < 64; kk += 32) {
      bf16x8 af[4], bfr[4];
      #pragma unroll
      for (int mi = 0; mi < 4; mi++) {
        int R = m_off + mi*16 + lr;
        af[mi] = *(const bf16x8*)&Asl[R*64 + ((kk + lk) ^ ((R & 7) << 3))];
      }
      #pragma unroll
      for (int ni = 0; ni < 4; ni++) {
        int R = n_off + ni*16 + lr;
        bfr[ni] = *(const bf16x8*)&Bsl[R*64 + ((kk + lk) ^ ((R & 7) << 3))];
      }
      #pragma unroll
      for (int mi = 0; mi < 4; mi++)
        #pragma unroll
        for (int ni = 0; ni < 4; ni++)
          acc[mi][ni] = __builtin_amdgcn_mfma_f32_16x16x32_bf16(
              af[mi], bfr[ni], acc[mi][ni], 0, 0, 0);
    }
  }

  // ---- epilogue: two 64-row halves through swizzled f32 LDS
  const int g = lane >> 4;
  #pragma unroll
  for (int half = 0; half < 2; half++) {
    __syncthreads();
    if ((wv >> 1) == half) {
      #pragma unroll
      for (int mi = 0; mi < 4; mi++)
        #pragma unroll
        for (int ni = 0; ni < 4; ni++)
          #pragma unroll
          for (int j = 0; j < 4; j++) {
            int lrow = mi*16 + 4*g + j;
            int col  = n_off + ni*16 + lr;
            Cf[lrow][col ^ ((lrow & 7) << 2)] = acc[mi][ni][j];
          }
    }
    __syncthreads();
    #pragma unroll
    for (int jj = 0; jj < 8; jj++) {
      int ch = tid + jj * 256;
      int r = ch >> 5, c4 = ch & 31;
      float4 v = *(const float4*)&Cf[r][(c4*4) ^ ((r & 7) << 2)];
      int grow = row0 + half*64 + r;
      int gcol = col0 + c4*4;
      if (EPI == 0 || EPI == 1) {
        float4 b4 = *(const float4*)&bias[gcol];
        float v0 = v.x + b4.x, v1 = v.y + b4.y, v2 = v.z + b4.z, v3 = v.w + b4.w;
        if (EPI == 1) { v0 = gelu_tanh(v0); v1 = gelu_tanh(v1); v2 = gelu_tanh(v2); v3 = gelu_tanh(v3); }
        uint2 o2;
        o2.x = (u32)f2b(v0) | ((u32)f2b(v1) << 16);
        o2.y = (u32)f2b(v2) | ((u32)f2b(v3) << 16);
        *(uint2*)(outb + (long)grow * Ntot + gcol) = o2;
      } else if (EPI == 2) {
        float4 b4 = *(const float4*)&bias[gcol];
        int n = grow % 49; int tq = grow / 49; int gg = tq & 63; int b_ = tq >> 6;
        int rr = n / 7, cc = n - 7 * rr;
        int hh = (gg >> 3) * 7 + rr, ww = (gg & 7) * 7 + cc;
        if (shift) { hh += 3; if (hh >= 56) hh -= 56; ww += 3; if (ww >= 56) ww -= 56; }
        long obase = ((long)((b_ * 56 + hh) * 56 + ww)) * 128;
        float4 res = *(const float4*)&resbase[obase + gcol];
        float4 o;
        o.x = res.x + v.x + b4.x; o.y = res.y + v.y + b4.y;
        o.z = res.z + v.z + b4.z; o.w = res.w + v.w + b4.w;
        *(float4*)&outf[obase + gcol] = o;
      } else if (EPI == 3) {
        float4 b4 = *(const float4*)&bias[gcol];
        float4 cur = *(const float4*)&outf[(long)grow * 128 + gcol];
        cur.x += v.x + b4.x; cur.y += v.y + b4.y;
        cur.z += v.z + b4.z; cur.w += v.w + b4.w;
        *(float4*)&outf[(long)grow * 128 + gcol] = cur;
      } else {
        *(float4*)&outf[(long)grow * Ntot + gcol] = v;
      }
    }
  }
}

extern "C" void kernel_launch(void* const* d_in, const int* in_sizes, int n_in,
                              void* d_out, int out_size, void* d_ws, size_t ws_size,
                              hipStream_t stream)
{
  const float* x_in   = (const float*)d_in[0];
  const float* ln1_g  = (const float*)d_in[1];
  const float* ln1_b  = (const float*)d_in[2];
  const float* qkv_w  = (const float*)d_in[3];
  const float* qkv_b  = (const float*)d_in[4];
  const float* proj_w = (const float*)d_in[5];
  const float* proj_b = (const float*)d_in[6];
  const float* ln2_g  = (const float*)d_in[7];
  const float* ln2_b  = (const float*)d_in[8];
  const float* w1     = (const float*)d_in[9];
  const float* b1     = (const float*)d_in[10];
  const float* w2     = (const float*)d_in[11];
  const float* b2     = (const float*)d_in[12];
  const float* dsg    = (const float*)d_in[13];
  const float* dsb    = (const float*)d_in[14];
  const float* dsw    = (const float*)d_in[15];

  float* x_ws   = (float*)d_ws;                          // [MTOK][128] f32
  u16* buf_h    = (u16*)(x_ws + (long)MTOK * 128);       // [MTOK][128] bf16
  u16* buf_o    = buf_h;                                 // alias (disjoint lifetimes)
  u16* buf_big  = buf_h + (long)MTOK * 128;              // [MTOK][512] bf16
  u16* wts      = buf_big + (long)MTOK * 512;
  u16* qkv_wt   = wts;                                   // [L][384][128]
  u16* proj_wt  = qkv_wt  + 2 * 49152;                   // [L][128][128]
  u16* w1t      = proj_wt + 2 * 16384;                   // [L][512][128]
  u16* w2t      = w1t     + 2 * 65536;                   // [L][128][512]
  u16* ds_wt    = w2t     + 2 * 65536;                   // [256][512]

  for (int i = 0; i < 2; i++) {
    transpose_cvt<<<(49152+255)/256, 256, 0, stream>>>(qkv_w  + i*49152, qkv_wt  + i*49152, 128, 384);
    transpose_cvt<<<(16384+255)/256, 256, 0, stream>>>(proj_w + i*16384, proj_wt + i*16384, 128, 128);
    transpose_cvt<<<(65536+255)/256, 256, 0, stream>>>(w1     + i*65536, w1t     + i*65536, 128, 512);
    transpose_cvt<<<(65536+255)/256, 256, 0, stream>>>(w2     + i*65536, w2t     + i*65536, 512, 128);
  }
  transpose_cvt<<<(131072+255)/256, 256, 0, stream>>>(dsw, ds_wt, 512, 256);

  for (int i = 0; i < 2; i++) {
    if (i == 0) ln_kernel<0><<<MTOK/4, 256, 0, stream>>>(x_in, ln1_g,       ln1_b,       buf_h);
    else        ln_kernel<1><<<MTOK/4, 256, 0, stream>>>(x_ws, ln1_g + 128, ln1_b + 128, buf_h);
    gemm_kernel<128,0><<<dim3(MTOK/128, 3), 256, 0, stream>>>(
        buf_h, qkv_wt + i*49152, qkv_b + i*384, 384, buf_big, nullptr, nullptr, 0);
    if (i == 0) attn_mfma<0><<<4096, 256, 0, stream>>>(buf_big, buf_o);
    else        attn_mfma<1><<<4096, 256, 0, stream>>>(buf_big, buf_o);
    gemm_kernel<128,2><<<dim3(MTOK/128, 1), 256, 0, stream>>>(
        buf_o, proj_wt + i*16384, proj_b + i*128, 128, nullptr, x_ws,
        (i == 0 ? x_in : (const float*)x_ws), i);
    ln_kernel<2><<<MTOK/4, 256, 0, stream>>>(x_ws, ln2_g + i*128, ln2_b + i*128, buf_h);
    gemm_kernel<128,1><<<dim3(MTOK/128, 4), 256, 0, stream>>>(
        buf_h, w1t + i*65536, b1 + i*512, 512, buf_big, nullptr, nullptr, 0);
    gemm_kernel<512,3><<<dim3(MTOK/128, 1), 256, 0, stream>>>(
        buf_big, w2t + i*65536, b2 + i*128, 128, nullptr, x_ws, x_ws, 0);
  }

  ds_ln_kernel<<<DSTOK/4, 256, 0, stream>>>(x_ws, dsg, dsb, buf_h);
  gemm_kernel<512,4><<<dim3(DSTOK/128, 2), 256, 0, stream>>>(
      buf_h, ds_wt, nullptr, 256, nullptr, (float*)d_out, nullptr, 0);
}